// Round 19
// baseline (243.503 us; speedup 1.0000x reference)
//
#include <hip/hip_runtime.h>
#include <hip/hip_bf16.h>
#include <stdint.h>

#define DEV static __device__ __forceinline__

typedef float f32x4 __attribute__((ext_vector_type(4)));
typedef __bf16 bf16x8 __attribute__((ext_vector_type(8)));
typedef unsigned short u16x8 __attribute__((ext_vector_type(8)));
typedef unsigned short u16x4 __attribute__((ext_vector_type(4)));
typedef uint32_t u32x4 __attribute__((ext_vector_type(4)));
typedef unsigned short u16;

#define B_ 2
#define L_ 2048
#define D_MODEL_ 1024
#define H_ 16
#define DH_ 64

// shift in base-2 score domain: 8 (base-e) * log2(e)
#define SHIFT2 11.5415603f

DEV u16 f2bf(float f) {
  union { float f; uint32_t u; } v; v.f = f;
  uint32_t r = v.u + 0x7FFFu + ((v.u >> 16) & 1u);  // RNE
  return (u16)(r >> 16);
}

DEV float exp2v(float x) {
#if __has_builtin(__builtin_amdgcn_exp2f)
  return __builtin_amdgcn_exp2f(x);
#else
  float r;
  asm("v_exp_f32 %0, %1" : "=v"(r) : "v"(x));
  return r;
#endif
}

// pack two f32 -> u32 of 2x bf16 (lo = a, hi = b), RNE
DEV uint32_t pkbf(float a, float b) {
  __hip_bfloat162 h = __float22bfloat162_rn(float2{a, b});
  union { __hip_bfloat162 h; uint32_t u; } cv; cv.h = h;
  return cv.u;
}

DEV f32x4 mfma16(bf16x8 a, bf16x8 b, f32x4 c) {
  return __builtin_amdgcn_mfma_f32_16x16x32_bf16(a, b, c, 0, 0, 0);
}

// async global->LDS, 16B per lane. LDS dest = wave-uniform base + lane*16.
DEV void gl_lds16(const void* g, void* l) {
  __builtin_amdgcn_global_load_lds(
      (const __attribute__((address_space(1))) unsigned int*)g,
      (__attribute__((address_space(3))) unsigned int*)l, 16, 0, 0);
}

// ---------------------------------------------------------------- cast f32->bf16 (src==null -> zero fill)
struct CastArgs {
  const float* src[8];
  u16* dst[8];
  int n8[8];
};

__global__ __launch_bounds__(256) void cast_kernel(CastArgs a) {
  const int z = blockIdx.z;
  u16* d = a.dst[z];
  const int n8 = a.n8[z];
  const int stride = gridDim.x * blockDim.x;
  const float* s = a.src[z];
  if (s == nullptr) {
    for (int i = blockIdx.x * blockDim.x + threadIdx.x; i < n8; i += stride)
      *((u16x8*)d + i) = u16x8{0, 0, 0, 0, 0, 0, 0, 0};
    return;
  }
  for (int i = blockIdx.x * blockDim.x + threadIdx.x; i < n8; i += stride) {
    const float4* sp = (const float4*)s + (size_t)i * 2;
    float4 x0 = sp[0], x1 = sp[1];
    u16x8 o;
    o[0] = f2bf(x0.x); o[1] = f2bf(x0.y); o[2] = f2bf(x0.z); o[3] = f2bf(x0.w);
    o[4] = f2bf(x1.x); o[5] = f2bf(x1.y); o[6] = f2bf(x1.z); o[7] = f2bf(x1.w);
    *((u16x8*)d + i) = o;
  }
}

// ---------------------------------------------------------------- GEMM  out = (X @ W^T + bias) * alpha
// mode 0: bf16 row-major out; mode 1: f32 row-major out
// mode 2: V fragment-order VF[bh][t][frag8][lane64][8] (bf16)
// mode 3: K fragment-order KF[bh][t][frag8][lane64][8] (bf16)
#define GM 4096
#define GN 1024
#define GK 1024

struct GemmArgs {
  const u16* X[3];
  const u16* W[3];
  const float* bias[3];
  void* out[3];
  float alpha[3];
  int mode[3];
};

__global__ __launch_bounds__(256) void gemm_bt(GemmArgs g) {
  const int z = blockIdx.z;
  const u16* X = g.X[z];
  const u16* W = g.W[z];
  const float* bias = g.bias[z];
  const float alpha = g.alpha[z];
  const int mode = g.mode[z];
  const int m0 = blockIdx.y * 128, n0 = blockIdx.x * 128;

  __shared__ __align__(16) char smem[32 * 1024];
  char* As = smem;            // [128 rows][128B] XOR-swizzled by ((r&7)<<4)
  char* Bs = smem + 16 * 1024;

  const int tid = threadIdx.x;
  const int lane = tid & 63, w = tid >> 6;
  const int l15 = lane & 15, l4 = lane >> 4;
  const int wm = (w >> 1) * 64, wn = (w & 1) * 64;

  f32x4 acc[4][4];
#pragma unroll
  for (int i = 0; i < 4; ++i)
#pragma unroll
    for (int j = 0; j < 4; ++j) acc[i][j] = f32x4{0.f, 0.f, 0.f, 0.f};

  for (int ks = 0; ks < GK; ks += 64) {
    __syncthreads();
    for (int c = w; c < 16; c += 4) {
      int r = c * 8 + (lane >> 3);
      int j = lane & 7;
      int sj = j ^ (r & 7);
      gl_lds16((const char*)(X + (size_t)(m0 + r) * GK + ks) + sj * 16, As + c * 1024);
      gl_lds16((const char*)(W + (size_t)(n0 + r) * GK + ks) + sj * 16, Bs + c * 1024);
    }
    __syncthreads();
#pragma unroll
    for (int ksub = 0; ksub < 2; ++ksub) {
      bf16x8 af[4], bfr[4];
#pragma unroll
      for (int mf = 0; mf < 4; ++mf) {
        int r = wm + mf * 16 + l15;
        int j16 = ksub * 4 + l4;
        af[mf] = *(const bf16x8*)(As + r * 128 + ((j16 ^ (r & 7)) * 16));
      }
#pragma unroll
      for (int nf = 0; nf < 4; ++nf) {
        int r = wn + nf * 16 + l15;
        int j16 = ksub * 4 + l4;
        bfr[nf] = *(const bf16x8*)(Bs + r * 128 + ((j16 ^ (r & 7)) * 16));
      }
#pragma unroll
      for (int mf = 0; mf < 4; ++mf)
#pragma unroll
        for (int nf = 0; nf < 4; ++nf) acc[mf][nf] = mfma16(af[mf], bfr[nf], acc[mf][nf]);
    }
  }

  if (mode == 2) {
    // V -> fragment-order VF (layout verified in R17)
    u16* base = (u16*)g.out[z];
#pragma unroll
    for (int nf = 0; nf < 4; ++nf) {
      int n = n0 + wn + nf * 16 + l15;
      float bv = bias[n];
      int df = (n & 63) >> 4, fl15 = n & 15, hh = n >> 6;
#pragma unroll
      for (int mf = 0; mf < 4; ++mf) {
        int m = m0 + wm + mf * 16 + l4 * 4;
        u16x4 pk;
#pragma unroll
        for (int r = 0; r < 4; ++r) pk[r] = f2bf((acc[mf][nf][r] + bv) * alpha);
        int lg = m & 2047, bb = m >> 11;
        int t = lg >> 6, lc = lg & 63;
        int c = lc >> 3, e = lc & 7;
        size_t off = ((((size_t)(bb * H_ + hh) * 32 + t) * 8 + (c >> 2) * 4 + df) * 512) +
                     ((c & 3) * 16 + fl15) * 8 + e;
        *(u16x4*)(base + off) = pk;
      }
    }
  } else if (mode == 3) {
    // K -> fragment-order KF (layout verified in R18)
    u16* base = (u16*)g.out[z];
#pragma unroll
    for (int nf = 0; nf < 4; ++nf) {
      int n = n0 + wn + nf * 16 + l15;
      float bv = bias[n];
      int dh = n & 63, hh = n >> 6;
      int c = dh >> 3;
      int fragb = (c >> 2) * 4, laneb = (c & 3) * 16, e = dh & 7;
#pragma unroll
      for (int mf = 0; mf < 4; ++mf) {
#pragma unroll
        for (int r = 0; r < 4; ++r) {
          int m = m0 + wm + mf * 16 + l4 * 4 + r;
          int lg = m & 2047, bb = m >> 11;
          int t = lg >> 6, nfk = (lg >> 4) & 3, l15k = lg & 15;
          size_t off = ((((size_t)(bb * H_ + hh) * 32 + t) * 8 + fragb + nfk) * 512) +
                       (laneb + l15k) * 8 + e;
          base[off] = f2bf((acc[mf][nf][r] + bv) * alpha);
        }
      }
    }
  } else {
#pragma unroll
    for (int nf = 0; nf < 4; ++nf) {
      int n = n0 + wn + nf * 16 + l15;
      float bv = bias[n];
#pragma unroll
      for (int mf = 0; mf < 4; ++mf) {
#pragma unroll
        for (int r = 0; r < 4; ++r) {
          int m = m0 + wm + mf * 16 + l4 * 4 + r;
          float val = (acc[mf][nf][r] + bv) * alpha;
          if (mode == 1)
            ((float*)g.out[z])[(size_t)m * GN + n] = val;
          else
            ((u16*)g.out[z])[(size_t)m * GN + n] = f2bf(val);
        }
      }
    }
  }
}

// ---------------------------------------------------------------- sum-exp kernel (barrier-free, fragment K, XCD-affine)
// Flat grid 4096; lid = (bid&7)*512 + bid>>3 gives each XCD 512 consecutive
// logical blocks = 4 complete heads, so each head's KF fragments live in ONE
// XCD's L2. sums[bh][row] += sum over 512-key chunk of 2^(s - SHIFT2).
__global__ __launch_bounds__(256) void sumexp_kernel(const u16* Qp, const u16* KF,
                                                     float* sums) {
  const int bid = blockIdx.x;
  const int lid = (bid & 7) * 512 + (bid >> 3);  // bijective: 4096 % 8 == 0
  const int q0 = (lid & 31) * 64;
  const int tb = ((lid >> 5) & 3) * 8;  // first key tile of this block's chunk
  const int bh = lid >> 7;
  const int b = bh >> 4, h = bh & 15;
  const int tid = threadIdx.x, lane = tid & 63, w = tid >> 6;
  const int l15 = lane & 15, l4 = lane >> 4;

  const u16* Qbase = Qp + ((size_t)(b * L_ + q0 + w * 16) * D_MODEL_ + h * DH_);
  const u16* Kf = KF + ((size_t)bh * 32) * 4096;

  bf16x8 qa[2];
#pragma unroll
  for (int ksub = 0; ksub < 2; ++ksub)
    qa[ksub] = *(const bf16x8*)(Qbase + (size_t)l15 * D_MODEL_ + (ksub * 4 + l4) * 8);

  float ssum = 0.f;
  for (int t = 0; t < 8; ++t) {
    const u16* Kt = Kf + (size_t)(tb + t) * 4096;
    f32x4 s[4];
#pragma unroll
    for (int nf = 0; nf < 4; ++nf) s[nf] = f32x4{0.f, 0.f, 0.f, 0.f};
    __builtin_amdgcn_s_setprio(1);
#pragma unroll
    for (int ksub = 0; ksub < 2; ++ksub) {
      bf16x8 kb[4];
#pragma unroll
      for (int nf = 0; nf < 4; ++nf)
        kb[nf] = *(const bf16x8*)(Kt + (ksub * 4 + nf) * 512 + lane * 8);
#pragma unroll
      for (int nf = 0; nf < 4; ++nf) s[nf] = mfma16(kb[nf], qa[ksub], s[nf]);
    }
    __builtin_amdgcn_s_setprio(0);
#pragma unroll
    for (int nf = 0; nf < 4; ++nf)
#pragma unroll
      for (int r = 0; r < 4; ++r) ssum += exp2v(s[nf][r] - SHIFT2);
  }

  // merge across l4 groups (lane's q-row = l15)
  ssum += __shfl_xor(ssum, 16);
  ssum += __shfl_xor(ssum, 32);
  if (lane < 16)
    atomicAdd(&sums[((size_t)bh << 11) + q0 + w * 16 + lane], ssum);
}

// ---------------------------------------------------------------- attention pass 2
// Barrier-free operand flow (fragment K+V, coalesced 1KB loads) with a RAW
// per-tile s_barrier (no vmcnt drain) to keep the block's 4 waves converged:
// they read the SAME K/V tile in the same order, so 3 of 4 waves hit L1 —
// ~4x L2-read reduction. NT transposed P stores; XCD-contiguous writes.
__global__ __launch_bounds__(256) void attn_kernel(const u16* Qp, const u16* KF,
                                                   const u16* VF, const float* sums,
                                                   float* attn, u16* ctx) {
  const int bid = blockIdx.x;
  const int lid = (bid & 7) * 128 + (bid >> 3);  // bijective: 1024 % 8 == 0
  const int q0 = (lid & 31) * 64;
  const int h = (lid >> 5) & 15;
  const int b = lid >> 9;
  const int tid = threadIdx.x, lane = tid & 63, w = tid >> 6;
  const int l15 = lane & 15, l4 = lane >> 4;

  __shared__ __align__(16) char smem[16 * 1024];  // Pf32 per wave
  char* Pw = smem + w * 4096;

  const u16* Qbase = Qp + ((size_t)(b * L_ + q0 + w * 16) * D_MODEL_ + h * DH_);
  const u16* Kf = KF + ((size_t)(b * H_ + h) * 32) * 4096;
  const u16* Vb = VF + ((size_t)(b * H_ + h) * 32) * 4096;
  float* attnb = attn + ((size_t)(b * H_ + h)) * L_ * L_;

  bf16x8 qa[2];
#pragma unroll
  for (int ksub = 0; ksub < 2; ++ksub)
    qa[ksub] = *(const bf16x8*)(Qbase + (size_t)l15 * D_MODEL_ + (ksub * 4 + l4) * 8);

  // per-lane normalizer from precomputed sums (lane's q-row = l15)
  const float c2 =
      SHIFT2 + __log2f(sums[(((size_t)(b * H_ + h)) << 11) + q0 + w * 16 + l15]);

  f32x4 cacc[4];
#pragma unroll
  for (int i = 0; i < 4; ++i) cacc[i] = f32x4{0.f, 0.f, 0.f, 0.f};

  const int swz = l15 & 7;
  float* awave = attnb + (size_t)(q0 + w * 16) * L_;

  for (int t = 0; t < 32; ++t) {
    const int c0 = t * 64;
    const u16* Kt = Kf + (size_t)t * 4096;
    const u16* Vt = Vb + (size_t)t * 4096;
    // coalesced fragment loads (1KB each); waves converged -> L1 reuse
    bf16x8 kb[2][4], va[2][4];
#pragma unroll
    for (int ksub = 0; ksub < 2; ++ksub)
#pragma unroll
      for (int i = 0; i < 4; ++i) {
        kb[ksub][i] = *(const bf16x8*)(Kt + (ksub * 4 + i) * 512 + lane * 8);
        va[ksub][i] = *(const bf16x8*)(Vt + (ksub * 4 + i) * 512 + lane * 8);
      }

    f32x4 s[4];
#pragma unroll
    for (int nf = 0; nf < 4; ++nf) s[nf] = f32x4{0.f, 0.f, 0.f, 0.f};
    __builtin_amdgcn_s_setprio(1);
#pragma unroll
    for (int ksub = 0; ksub < 2; ++ksub)
#pragma unroll
      for (int nf = 0; nf < 4; ++nf) s[nf] = mfma16(kb[ksub][nf], qa[ksub], s[nf]);
    __builtin_amdgcn_s_setprio(0);

    // p = 2^(s - c2) -> Pf32 LDS (wave-private, in-order DS)
#pragma unroll
    for (int nf = 0; nf < 4; ++nf) {
      f32x4 p4;
#pragma unroll
      for (int r = 0; r < 4; ++r) p4[r] = exp2v(s[nf][r] - c2);
      *(f32x4*)(Pw + l15 * 256 + (((nf * 4 + l4) ^ swz) * 16)) = p4;
    }
    // transposed read -> full-line nontemporal global stores
#pragma unroll
    for (int j = 0; j < 4; ++j) {
      int row = 4 * j + (lane >> 4);
      f32x4 v = *(const f32x4*)(Pw + row * 256 + (((lane & 15) ^ (row & 7)) * 16));
      __builtin_nontemporal_store(
          v, (f32x4*)(awave + (size_t)row * L_ + c0 + (lane & 15) * 4));
    }
    // PV: rebuild pa from Pf32 (pairs -> bf16), accumulate with coalesced-V regs
    __builtin_amdgcn_s_setprio(1);
#pragma unroll
    for (int ksub = 0; ksub < 2; ++ksub) {
      int cbase = (ksub * 4 + l4) * 2;
      f32x4 plo = *(const f32x4*)(Pw + l15 * 256 + ((cbase ^ swz) * 16));
      f32x4 phi = *(const f32x4*)(Pw + l15 * 256 + (((cbase + 1) ^ swz) * 16));
      union { u32x4 u; bf16x8 h; } pa;
      pa.u[0] = pkbf(plo[0], plo[1]);
      pa.u[1] = pkbf(plo[2], plo[3]);
      pa.u[2] = pkbf(phi[0], phi[1]);
      pa.u[3] = pkbf(phi[2], phi[3]);
#pragma unroll
      for (int df = 0; df < 4; ++df)
        cacc[df] = mfma16(pa.h, va[ksub][df], cacc[df]);
    }
    __builtin_amdgcn_s_setprio(0);
    // RAW barrier (no waitcnt drain): keeps the 4 waves phase-aligned so
    // their identical K/V tile reads hit L1.
    __builtin_amdgcn_s_barrier();
  }

  // ctx write (bf16): row = q0 + w*16 + 4*l4 + r, col = h*64 + df*16 + l15
#pragma unroll
  for (int df = 0; df < 4; ++df) {
#pragma unroll
    for (int r = 0; r < 4; ++r) {
      int row = q0 + w * 16 + l4 * 4 + r;
      int col = h * DH_ + df * 16 + l15;
      ctx[(size_t)(b * L_ + row) * D_MODEL_ + col] = f2bf(cacc[df][r]);
    }
  }
}

// ---------------------------------------------------------------- launch
extern "C" void kernel_launch(void* const* d_in, const int* in_sizes, int n_in,
                              void* d_out, int out_size, void* d_ws, size_t ws_size,
                              hipStream_t stream) {
  const float* q = (const float*)d_in[0];
  const float* k = (const float*)d_in[1];
  const float* v = (const float*)d_in[2];
  const float* w_q = (const float*)d_in[3];
  const float* b_q = (const float*)d_in[4];
  const float* w_k = (const float*)d_in[5];
  const float* b_k = (const float*)d_in[6];
  const float* w_v = (const float*)d_in[7];
  const float* b_v = (const float*)d_in[8];
  const float* w_o = (const float*)d_in[9];
  const float* b_o = (const float*)d_in[10];

  float* out = (float*)d_out;
  float* attn = (float*)d_out + (size_t)B_ * L_ * D_MODEL_;

  const size_t MB = 1u << 20;
  char* ws = (char*)d_ws;
  u16* qb = (u16*)(ws + 0 * MB);
  u16* kb = (u16*)(ws + 8 * MB);    // reused as ctx(bf16) after QKV GEMM
  u16* vb = (u16*)(ws + 16 * MB);
  u16* wqb = (u16*)(ws + 24 * MB);
  u16* wkb = (u16*)(ws + 26 * MB);
  u16* wvb = (u16*)(ws + 28 * MB);
  u16* wob = (u16*)(ws + 30 * MB);
  u16* Qp = (u16*)(ws + 32 * MB);
  u16* KF = (u16*)(ws + 40 * MB);        // fragment-order K, 8MB
  u16* VF = (u16*)(ws + 48 * MB);        // fragment-order V, 8MB
  float* sums = (float*)(ws + 56 * MB);  // B*H*L f32 = 256KB
  u16* ctx = kb;

  // 1. cast everything to bf16 (+ zero sums)
  CastArgs ca;
  ca.src[0] = q;   ca.dst[0] = qb;  ca.n8[0] = (B_ * L_ * D_MODEL_) / 8;
  ca.src[1] = k;   ca.dst[1] = kb;  ca.n8[1] = (B_ * L_ * D_MODEL_) / 8;
  ca.src[2] = v;   ca.dst[2] = vb;  ca.n8[2] = (B_ * L_ * D_MODEL_) / 8;
  ca.src[3] = w_q; ca.dst[3] = wqb; ca.n8[3] = (D_MODEL_ * D_MODEL_) / 8;
  ca.src[4] = w_k; ca.dst[4] = wkb; ca.n8[4] = (D_MODEL_ * D_MODEL_) / 8;
  ca.src[5] = w_v; ca.dst[5] = wvb; ca.n8[5] = (D_MODEL_ * D_MODEL_) / 8;
  ca.src[6] = w_o; ca.dst[6] = wob; ca.n8[6] = (D_MODEL_ * D_MODEL_) / 8;
  ca.src[7] = nullptr; ca.dst[7] = (u16*)sums; ca.n8[7] = (B_ * H_ * L_ * 4) / 16;
  cast_kernel<<<dim3(1024, 1, 8), 256, 0, stream>>>(ca);

  // 2. QKV projections. Q row-major; K,V fragment-order.
  GemmArgs ga;
  ga.X[0] = qb;  ga.W[0] = wqb; ga.bias[0] = b_q; ga.out[0] = Qp; ga.alpha[0] = 0.125f * 1.44269504f; ga.mode[0] = 0;
  ga.X[1] = kb;  ga.W[1] = wkb; ga.bias[1] = b_k; ga.out[1] = KF; ga.alpha[1] = 1.f;    ga.mode[1] = 3;
  ga.X[2] = vb;  ga.W[2] = wvb; ga.bias[2] = b_v; ga.out[2] = VF; ga.alpha[2] = 1.f;    ga.mode[2] = 2;
  gemm_bt<<<dim3(8, 32, 3), 256, 0, stream>>>(ga);

  // 3a. row sums of 2^(s-SHIFT2): barrier-free fragment-K, XCD-affine
  sumexp_kernel<<<dim3(4096, 1, 1), 256, 0, stream>>>(Qp, KF, sums);

  // 3b. attention pass 2: fragment operands + L1-convergence barrier
  attn_kernel<<<dim3(1024, 1, 1), 256, 0, stream>>>(Qp, KF, VF, sums, attn, ctx);

  // 4. output projection (f32 out + bias)
  GemmArgs go;
  go.X[0] = ctx; go.W[0] = wob; go.bias[0] = b_o; go.out[0] = out; go.alpha[0] = 1.f; go.mode[0] = 1;
  go.X[1] = ctx; go.W[1] = wob; go.bias[1] = b_o; go.out[1] = out; go.alpha[1] = 1.f; go.mode[1] = 1;
  go.X[2] = ctx; go.W[2] = wob; go.bias[2] = b_o; go.out[2] = out; go.alpha[2] = 1.f; go.mode[2] = 1;
  gemm_bt<<<dim3(8, 32, 1), 256, 0, stream>>>(go);
}

// Round 20
// 228.817 us; speedup vs baseline: 1.0642x; 1.0642x over previous
//
#include <hip/hip_runtime.h>
#include <hip/hip_bf16.h>
#include <stdint.h>

#define DEV static __device__ __forceinline__

typedef float f32x4 __attribute__((ext_vector_type(4)));
typedef __bf16 bf16x8 __attribute__((ext_vector_type(8)));
typedef unsigned short u16x8 __attribute__((ext_vector_type(8)));
typedef unsigned short u16x4 __attribute__((ext_vector_type(4)));
typedef uint32_t u32x4 __attribute__((ext_vector_type(4)));
typedef unsigned short u16;

#define B_ 2
#define L_ 2048
#define D_MODEL_ 1024
#define H_ 16
#define DH_ 64

// shift in base-2 score domain: 8 (base-e) * log2(e)
#define SHIFT2 11.5415603f

DEV u16 f2bf(float f) {
  union { float f; uint32_t u; } v; v.f = f;
  uint32_t r = v.u + 0x7FFFu + ((v.u >> 16) & 1u);  // RNE
  return (u16)(r >> 16);
}

DEV float exp2v(float x) {
#if __has_builtin(__builtin_amdgcn_exp2f)
  return __builtin_amdgcn_exp2f(x);
#else
  float r;
  asm("v_exp_f32 %0, %1" : "=v"(r) : "v"(x));
  return r;
#endif
}

// pack two f32 -> u32 of 2x bf16 (lo = a, hi = b), RNE
DEV uint32_t pkbf(float a, float b) {
  __hip_bfloat162 h = __float22bfloat162_rn(float2{a, b});
  union { __hip_bfloat162 h; uint32_t u; } cv; cv.h = h;
  return cv.u;
}

DEV f32x4 mfma16(bf16x8 a, bf16x8 b, f32x4 c) {
  return __builtin_amdgcn_mfma_f32_16x16x32_bf16(a, b, c, 0, 0, 0);
}

// async global->LDS, 16B per lane. LDS dest = wave-uniform base + lane*16.
DEV void gl_lds16(const void* g, void* l) {
  __builtin_amdgcn_global_load_lds(
      (const __attribute__((address_space(1))) unsigned int*)g,
      (__attribute__((address_space(3))) unsigned int*)l, 16, 0, 0);
}

// ---------------------------------------------------------------- cast f32->bf16
struct CastArgs {
  const float* src[7];
  u16* dst[7];
  int n8[7];
};

__global__ __launch_bounds__(256) void cast_kernel(CastArgs a) {
  const int z = blockIdx.z;
  u16* d = a.dst[z];
  const int n8 = a.n8[z];
  const int stride = gridDim.x * blockDim.x;
  const float* s = a.src[z];
  for (int i = blockIdx.x * blockDim.x + threadIdx.x; i < n8; i += stride) {
    const float4* sp = (const float4*)s + (size_t)i * 2;
    float4 x0 = sp[0], x1 = sp[1];
    u16x8 o;
    o[0] = f2bf(x0.x); o[1] = f2bf(x0.y); o[2] = f2bf(x0.z); o[3] = f2bf(x0.w);
    o[4] = f2bf(x1.x); o[5] = f2bf(x1.y); o[6] = f2bf(x1.z); o[7] = f2bf(x1.w);
    *((u16x8*)d + i) = o;
  }
}

// ---------------------------------------------------------------- GEMM  out = (X @ W^T + bias) * alpha
// mode 0: bf16 row-major out; mode 1: f32 row-major out
// mode 2: V fragment-order VF[bh][t][frag8][lane64][8] (bf16)
// mode 3: K fragment-order KF[bh][t][frag8][lane64][8] (bf16)
#define GM 4096
#define GN 1024
#define GK 1024

struct GemmArgs {
  const u16* X[3];
  const u16* W[3];
  const float* bias[3];
  void* out[3];
  float alpha[3];
  int mode[3];
};

__global__ __launch_bounds__(256) void gemm_bt(GemmArgs g) {
  const int z = blockIdx.z;
  const u16* X = g.X[z];
  const u16* W = g.W[z];
  const float* bias = g.bias[z];
  const float alpha = g.alpha[z];
  const int mode = g.mode[z];
  const int m0 = blockIdx.y * 128, n0 = blockIdx.x * 128;

  __shared__ __align__(16) char smem[32 * 1024];
  char* As = smem;            // [128 rows][128B] XOR-swizzled by ((r&7)<<4)
  char* Bs = smem + 16 * 1024;

  const int tid = threadIdx.x;
  const int lane = tid & 63, w = tid >> 6;
  const int l15 = lane & 15, l4 = lane >> 4;
  const int wm = (w >> 1) * 64, wn = (w & 1) * 64;

  f32x4 acc[4][4];
#pragma unroll
  for (int i = 0; i < 4; ++i)
#pragma unroll
    for (int j = 0; j < 4; ++j) acc[i][j] = f32x4{0.f, 0.f, 0.f, 0.f};

  for (int ks = 0; ks < GK; ks += 64) {
    __syncthreads();
    for (int c = w; c < 16; c += 4) {
      int r = c * 8 + (lane >> 3);
      int j = lane & 7;
      int sj = j ^ (r & 7);
      gl_lds16((const char*)(X + (size_t)(m0 + r) * GK + ks) + sj * 16, As + c * 1024);
      gl_lds16((const char*)(W + (size_t)(n0 + r) * GK + ks) + sj * 16, Bs + c * 1024);
    }
    __syncthreads();
#pragma unroll
    for (int ksub = 0; ksub < 2; ++ksub) {
      bf16x8 af[4], bfr[4];
#pragma unroll
      for (int mf = 0; mf < 4; ++mf) {
        int r = wm + mf * 16 + l15;
        int j16 = ksub * 4 + l4;
        af[mf] = *(const bf16x8*)(As + r * 128 + ((j16 ^ (r & 7)) * 16));
      }
#pragma unroll
      for (int nf = 0; nf < 4; ++nf) {
        int r = wn + nf * 16 + l15;
        int j16 = ksub * 4 + l4;
        bfr[nf] = *(const bf16x8*)(Bs + r * 128 + ((j16 ^ (r & 7)) * 16));
      }
#pragma unroll
      for (int mf = 0; mf < 4; ++mf)
#pragma unroll
        for (int nf = 0; nf < 4; ++nf) acc[mf][nf] = mfma16(af[mf], bfr[nf], acc[mf][nf]);
    }
  }

  if (mode == 2) {
    // V -> fragment-order VF (layout verified in R17)
    u16* base = (u16*)g.out[z];
#pragma unroll
    for (int nf = 0; nf < 4; ++nf) {
      int n = n0 + wn + nf * 16 + l15;
      float bv = bias[n];
      int df = (n & 63) >> 4, fl15 = n & 15, hh = n >> 6;
#pragma unroll
      for (int mf = 0; mf < 4; ++mf) {
        int m = m0 + wm + mf * 16 + l4 * 4;
        u16x4 pk;
#pragma unroll
        for (int r = 0; r < 4; ++r) pk[r] = f2bf((acc[mf][nf][r] + bv) * alpha);
        int lg = m & 2047, bb = m >> 11;
        int t = lg >> 6, lc = lg & 63;
        int c = lc >> 3, e = lc & 7;
        size_t off = ((((size_t)(bb * H_ + hh) * 32 + t) * 8 + (c >> 2) * 4 + df) * 512) +
                     ((c & 3) * 16 + fl15) * 8 + e;
        *(u16x4*)(base + off) = pk;
      }
    }
  } else if (mode == 3) {
    // K -> fragment-order KF (layout verified in R18)
    u16* base = (u16*)g.out[z];
#pragma unroll
    for (int nf = 0; nf < 4; ++nf) {
      int n = n0 + wn + nf * 16 + l15;
      float bv = bias[n];
      int dh = n & 63, hh = n >> 6;
      int c = dh >> 3;
      int fragb = (c >> 2) * 4, laneb = (c & 3) * 16, e = dh & 7;
#pragma unroll
      for (int mf = 0; mf < 4; ++mf) {
#pragma unroll
        for (int r = 0; r < 4; ++r) {
          int m = m0 + wm + mf * 16 + l4 * 4 + r;
          int lg = m & 2047, bb = m >> 11;
          int t = lg >> 6, nfk = (lg >> 4) & 3, l15k = lg & 15;
          size_t off = ((((size_t)(bb * H_ + hh) * 32 + t) * 8 + fragb + nfk) * 512) +
                       (laneb + l15k) * 8 + e;
          base[off] = f2bf((acc[mf][nf][r] + bv) * alpha);
        }
      }
    }
  } else {
#pragma unroll
    for (int nf = 0; nf < 4; ++nf) {
      int n = n0 + wn + nf * 16 + l15;
      float bv = bias[n];
#pragma unroll
      for (int mf = 0; mf < 4; ++mf) {
#pragma unroll
        for (int r = 0; r < 4; ++r) {
          int m = m0 + wm + mf * 16 + l4 * 4 + r;
          float val = (acc[mf][nf][r] + bv) * alpha;
          if (mode == 1)
            ((float*)g.out[z])[(size_t)m * GN + n] = val;
          else
            ((u16*)g.out[z])[(size_t)m * GN + n] = f2bf(val);
        }
      }
    }
  }
}

// ---------------------------------------------------------------- fused attention (single kernel)
// Pass 1: 32-tile QK^T + exp2 accumulate (fragment-K coalesced loads, no V,
// no barriers), 2-shuffle merge -> c2 in registers. Pass 2: R18's exact
// barrier-free structure (fragment K+V 1KB loads, wave-private Pf32
// transpose, full-line NT stores, XCD-contiguous write spans).
// No sums buffer, no atomics, no extra kernel launch.
__global__ __launch_bounds__(256) void attn_kernel(const u16* Qp, const u16* KF,
                                                   const u16* VF, float* attn,
                                                   u16* ctx) {
  const int bid = blockIdx.x;
  const int lid = (bid & 7) * 128 + (bid >> 3);  // bijective: 1024 % 8 == 0
  const int q0 = (lid & 31) * 64;
  const int h = (lid >> 5) & 15;
  const int b = lid >> 9;
  const int tid = threadIdx.x, lane = tid & 63, w = tid >> 6;
  const int l15 = lane & 15, l4 = lane >> 4;

  __shared__ __align__(16) char smem[16 * 1024];  // Pf32 per wave
  char* Pw = smem + w * 4096;

  const u16* Qbase = Qp + ((size_t)(b * L_ + q0 + w * 16) * D_MODEL_ + h * DH_);
  const u16* Kf = KF + ((size_t)(b * H_ + h) * 32) * 4096;
  const u16* Vb = VF + ((size_t)(b * H_ + h) * 32) * 4096;
  float* attnb = attn + ((size_t)(b * H_ + h)) * L_ * L_;

  bf16x8 qa[2];
#pragma unroll
  for (int ksub = 0; ksub < 2; ++ksub)
    qa[ksub] = *(const bf16x8*)(Qbase + (size_t)l15 * D_MODEL_ + (ksub * 4 + l4) * 8);

  // ---- pass 1: per-lane sum of 2^(s - SHIFT2) over all 32 tiles
  float ssum = 0.f;
  for (int t = 0; t < 32; ++t) {
    const u16* Kt = Kf + (size_t)t * 4096;
    bf16x8 kb[2][4];
#pragma unroll
    for (int ksub = 0; ksub < 2; ++ksub)
#pragma unroll
      for (int i = 0; i < 4; ++i)
        kb[ksub][i] = *(const bf16x8*)(Kt + (ksub * 4 + i) * 512 + lane * 8);
    f32x4 s[4];
#pragma unroll
    for (int nf = 0; nf < 4; ++nf) s[nf] = f32x4{0.f, 0.f, 0.f, 0.f};
    __builtin_amdgcn_s_setprio(1);
#pragma unroll
    for (int ksub = 0; ksub < 2; ++ksub)
#pragma unroll
      for (int nf = 0; nf < 4; ++nf) s[nf] = mfma16(kb[ksub][nf], qa[ksub], s[nf]);
    __builtin_amdgcn_s_setprio(0);
#pragma unroll
    for (int nf = 0; nf < 4; ++nf)
#pragma unroll
      for (int r = 0; r < 4; ++r) ssum += exp2v(s[nf][r] - SHIFT2);
  }
  // merge across l4 groups (lane's q-row = l15)
  ssum += __shfl_xor(ssum, 16);
  ssum += __shfl_xor(ssum, 32);
  const float c2 = SHIFT2 + __log2f(ssum);

  f32x4 cacc[4];
#pragma unroll
  for (int i = 0; i < 4; ++i) cacc[i] = f32x4{0.f, 0.f, 0.f, 0.f};

  const int swz = l15 & 7;
  float* awave = attnb + (size_t)(q0 + w * 16) * L_;

  // ---- pass 2: recompute S^T, write normalized P, accumulate PV
  for (int t = 0; t < 32; ++t) {
    const int c0 = t * 64;
    const u16* Kt = Kf + (size_t)t * 4096;
    const u16* Vt = Vb + (size_t)t * 4096;
    bf16x8 kb[2][4], va[2][4];
#pragma unroll
    for (int ksub = 0; ksub < 2; ++ksub)
#pragma unroll
      for (int i = 0; i < 4; ++i) {
        kb[ksub][i] = *(const bf16x8*)(Kt + (ksub * 4 + i) * 512 + lane * 8);
        va[ksub][i] = *(const bf16x8*)(Vt + (ksub * 4 + i) * 512 + lane * 8);
      }

    f32x4 s[4];
#pragma unroll
    for (int nf = 0; nf < 4; ++nf) s[nf] = f32x4{0.f, 0.f, 0.f, 0.f};
    __builtin_amdgcn_s_setprio(1);
#pragma unroll
    for (int ksub = 0; ksub < 2; ++ksub)
#pragma unroll
      for (int nf = 0; nf < 4; ++nf) s[nf] = mfma16(kb[ksub][nf], qa[ksub], s[nf]);
    __builtin_amdgcn_s_setprio(0);

    // p = 2^(s - c2) -> Pf32 LDS (wave-private, in-order DS)
#pragma unroll
    for (int nf = 0; nf < 4; ++nf) {
      f32x4 p4;
#pragma unroll
      for (int r = 0; r < 4; ++r) p4[r] = exp2v(s[nf][r] - c2);
      *(f32x4*)(Pw + l15 * 256 + (((nf * 4 + l4) ^ swz) * 16)) = p4;
    }
    // transposed read -> full-line nontemporal global stores
#pragma unroll
    for (int j = 0; j < 4; ++j) {
      int row = 4 * j + (lane >> 4);
      f32x4 v = *(const f32x4*)(Pw + row * 256 + (((lane & 15) ^ (row & 7)) * 16));
      __builtin_nontemporal_store(
          v, (f32x4*)(awave + (size_t)row * L_ + c0 + (lane & 15) * 4));
    }
    // PV: rebuild pa from Pf32 (pairs -> bf16), accumulate with coalesced-V regs
    __builtin_amdgcn_s_setprio(1);
#pragma unroll
    for (int ksub = 0; ksub < 2; ++ksub) {
      int cbase = (ksub * 4 + l4) * 2;
      f32x4 plo = *(const f32x4*)(Pw + l15 * 256 + ((cbase ^ swz) * 16));
      f32x4 phi = *(const f32x4*)(Pw + l15 * 256 + (((cbase + 1) ^ swz) * 16));
      union { u32x4 u; bf16x8 h; } pa;
      pa.u[0] = pkbf(plo[0], plo[1]);
      pa.u[1] = pkbf(plo[2], plo[3]);
      pa.u[2] = pkbf(phi[0], phi[1]);
      pa.u[3] = pkbf(phi[2], phi[3]);
#pragma unroll
      for (int df = 0; df < 4; ++df)
        cacc[df] = mfma16(pa.h, va[ksub][df], cacc[df]);
    }
    __builtin_amdgcn_s_setprio(0);
  }

  // ctx write (bf16): row = q0 + w*16 + 4*l4 + r, col = h*64 + df*16 + l15
#pragma unroll
  for (int df = 0; df < 4; ++df) {
#pragma unroll
    for (int r = 0; r < 4; ++r) {
      int row = q0 + w * 16 + l4 * 4 + r;
      int col = h * DH_ + df * 16 + l15;
      ctx[(size_t)(b * L_ + row) * D_MODEL_ + col] = f2bf(cacc[df][r]);
    }
  }
}

// ---------------------------------------------------------------- launch
extern "C" void kernel_launch(void* const* d_in, const int* in_sizes, int n_in,
                              void* d_out, int out_size, void* d_ws, size_t ws_size,
                              hipStream_t stream) {
  const float* q = (const float*)d_in[0];
  const float* k = (const float*)d_in[1];
  const float* v = (const float*)d_in[2];
  const float* w_q = (const float*)d_in[3];
  const float* b_q = (const float*)d_in[4];
  const float* w_k = (const float*)d_in[5];
  const float* b_k = (const float*)d_in[6];
  const float* w_v = (const float*)d_in[7];
  const float* b_v = (const float*)d_in[8];
  const float* w_o = (const float*)d_in[9];
  const float* b_o = (const float*)d_in[10];

  float* out = (float*)d_out;
  float* attn = (float*)d_out + (size_t)B_ * L_ * D_MODEL_;

  const size_t MB = 1u << 20;
  char* ws = (char*)d_ws;
  u16* qb = (u16*)(ws + 0 * MB);
  u16* kb = (u16*)(ws + 8 * MB);    // reused as ctx(bf16) after QKV GEMM
  u16* vb = (u16*)(ws + 16 * MB);
  u16* wqb = (u16*)(ws + 24 * MB);
  u16* wkb = (u16*)(ws + 26 * MB);
  u16* wvb = (u16*)(ws + 28 * MB);
  u16* wob = (u16*)(ws + 30 * MB);
  u16* Qp = (u16*)(ws + 32 * MB);
  u16* KF = (u16*)(ws + 40 * MB);        // fragment-order K, 8MB
  u16* VF = (u16*)(ws + 48 * MB);        // fragment-order V, 8MB
  u16* ctx = kb;

  // 1. cast everything to bf16
  CastArgs ca;
  ca.src[0] = q;   ca.dst[0] = qb;  ca.n8[0] = (B_ * L_ * D_MODEL_) / 8;
  ca.src[1] = k;   ca.dst[1] = kb;  ca.n8[1] = (B_ * L_ * D_MODEL_) / 8;
  ca.src[2] = v;   ca.dst[2] = vb;  ca.n8[2] = (B_ * L_ * D_MODEL_) / 8;
  ca.src[3] = w_q; ca.dst[3] = wqb; ca.n8[3] = (D_MODEL_ * D_MODEL_) / 8;
  ca.src[4] = w_k; ca.dst[4] = wkb; ca.n8[4] = (D_MODEL_ * D_MODEL_) / 8;
  ca.src[5] = w_v; ca.dst[5] = wvb; ca.n8[5] = (D_MODEL_ * D_MODEL_) / 8;
  ca.src[6] = w_o; ca.dst[6] = wob; ca.n8[6] = (D_MODEL_ * D_MODEL_) / 8;
  cast_kernel<<<dim3(1024, 1, 7), 256, 0, stream>>>(ca);

  // 2. QKV projections. Q row-major; K,V fragment-order.
  GemmArgs ga;
  ga.X[0] = qb;  ga.W[0] = wqb; ga.bias[0] = b_q; ga.out[0] = Qp; ga.alpha[0] = 0.125f * 1.44269504f; ga.mode[0] = 0;
  ga.X[1] = kb;  ga.W[1] = wkb; ga.bias[1] = b_k; ga.out[1] = KF; ga.alpha[1] = 1.f;    ga.mode[1] = 3;
  ga.X[2] = vb;  ga.W[2] = wvb; ga.bias[2] = b_v; ga.out[2] = VF; ga.alpha[2] = 1.f;    ga.mode[2] = 2;
  gemm_bt<<<dim3(8, 32, 3), 256, 0, stream>>>(ga);

  // 3. fused attention: pass1 (sum) + pass2 (P out + ctx), single kernel
  attn_kernel<<<dim3(1024, 1, 1), 256, 0, stream>>>(Qp, KF, VF, attn, ctx);

  // 4. output projection (f32 out + bias)
  GemmArgs go;
  go.X[0] = ctx; go.W[0] = wob; go.bias[0] = b_o; go.out[0] = out; go.alpha[0] = 1.f; go.mode[0] = 1;
  go.X[1] = ctx; go.W[1] = wob; go.bias[1] = b_o; go.out[1] = out; go.alpha[1] = 1.f; go.mode[1] = 1;
  go.X[2] = ctx; go.W[2] = wob; go.bias[2] = b_o; go.out[2] = out; go.alpha[2] = 1.f; go.mode[2] = 1;
  gemm_bt<<<dim3(8, 32, 1), 256, 0, stream>>>(go);
}